// Round 7
// baseline (142.995 us; speedup 1.0000x reference)
//
#include <hip/hip_runtime.h>
#include <hip/hip_bf16.h>

typedef short s8v __attribute__((ext_vector_type(8)));   // 8 bf16 in 4 VGPRs
typedef short s4v __attribute__((ext_vector_type(4)));   // 4 bf16
typedef float f4v __attribute__((ext_vector_type(4)));   // MFMA accumulator

#define MFMA16(a,b,c) __builtin_amdgcn_mfma_f32_16x16x32_bf16((a),(b),(c),0,0,0)

__device__ __forceinline__ short f2bf(float f) {
    __hip_bfloat16 h = __float2bfloat16(f);
    short s; __builtin_memcpy(&s, &h, 2); return s;
}
__device__ __forceinline__ float bf2f(short s) {
    unsigned int u = ((unsigned int)(unsigned short)s) << 16;
    float f; __builtin_memcpy(&f, &u, 4); return f;
}
__device__ __forceinline__ s4v cvt4(float4 a) {
    s4v r; r[0] = f2bf(a.x); r[1] = f2bf(a.y); r[2] = f2bf(a.z); r[3] = f2bf(a.w);
    return r;
}

// ---------------------------------------------------------------------------
// Kernel 0: repack wq/wk/wv [1024,64] fp32 -> bf16 B-fragment layout.
// Frag id = ((t*32)+ks)*64 + lane, t = m3*4+nt. Lane holds
// B[k = ks*32 + (lane>>4)*8 + j][col = nt*16 + (lane&15)], j=0..7.
// Scale 1/32 (C^-0.5) baked into wq.
// ---------------------------------------------------------------------------
__global__ __launch_bounds__(256) void pack_w_kernel(
    const float* __restrict__ wq, const float* __restrict__ wk,
    const float* __restrict__ wv, short* __restrict__ wpack)
{
    int fid  = blockIdx.x * 256 + threadIdx.x;   // 0..24575
    int lane = fid & 63;
    int ks   = (fid >> 6) & 31;
    int t    = fid >> 11;                        // 0..11
    int m3 = t >> 2, nt = t & 3;
    int col = nt * 16 + (lane & 15);
    int k0  = ks * 32 + (lane >> 4) * 8;
    const float* w = (m3 == 0) ? wq : (m3 == 1 ? wk : wv);
    float sc = (m3 == 0) ? 0.03125f : 1.0f;
    s8v frag;
#pragma unroll
    for (int j = 0; j < 8; j++) frag[j] = f2bf(w[(k0 + j) * 64 + col] * sc);
    ((s8v*)wpack)[fid] = frag;
}

// ---------------------------------------------------------------------------
// Kernel 1: unified QKV GEMM. grid(256) x 512 thr (8 waves).
// Block = 64 token rows x 192 cols -> wpack L2 traffic halved vs 32-row
// blocks (98 MB total; wave pairs share tiles through L1). Wave w: rows
// (w&1)*32..+31 (2 row-frags), tiles (w>>1)*3..+2. 16 stages of 64 k;
// staging lane-contiguous (4 segments/wave-instr), register->LDS ping-pong,
// ONE barrier per stage. LDS stride 72 shorts (16B-aligned b128, rows
// spread over banks at stride 4 -> worst 2-way = free).
// V stored TRANSPOSED vt[b][dim][key], s4v-packed.
// ---------------------------------------------------------------------------
__global__ __launch_bounds__(512) void qkv_kernel(
    const float* __restrict__ x, const short* __restrict__ wpack,
    const float* __restrict__ bq, const float* __restrict__ bk,
    const float* __restrict__ bv,
    short* __restrict__ qws, short* __restrict__ kws, short* __restrict__ vt)
{
    __shared__ short xl[2][64][72];      // 18432 B

    int tid  = threadIdx.x;
    int wave = tid >> 6, lane = tid & 63;
    int quad = lane >> 4, l16 = lane & 15;
    int row0 = blockIdx.x * 64;
    int rhalf = (wave & 1) * 32;         // wave's 32-row half
    int tbase = (wave >> 1) * 3;         // wave's 3 wp tiles
    const float* xbase = x + (size_t)row0 * 1024;
    const s8v* wp = (const s8v*)wpack;

    f4v acc[2][3];
    f4v z = {0.f, 0.f, 0.f, 0.f};
#pragma unroll
    for (int rf = 0; rf < 2; rf++)
#pragma unroll
        for (int i = 0; i < 3; i++) acc[rf][i] = z;

    float4 xr[2];
    // prologue: stage slice 0. idx -> row=idx>>4, 16B-col=(idx&15)
#pragma unroll
    for (int i = 0; i < 2; i++) {
        int idx = i * 512 + tid;
        xr[i] = *(const float4*)(xbase + (size_t)(idx >> 4) * 1024 + (idx & 15) * 4);
    }
#pragma unroll
    for (int i = 0; i < 2; i++) {
        int idx = i * 512 + tid;
        *(s4v*)&xl[0][idx >> 4][(idx & 15) * 4] = cvt4(xr[i]);
    }
    __syncthreads();

    for (int sk = 0; sk < 16; sk++) {
        int cur = sk & 1, nxt = cur ^ 1;
        if (sk < 15) {                    // issue next slice's global loads
#pragma unroll
            for (int i = 0; i < 2; i++) {
                int idx = i * 512 + tid;
                xr[i] = *(const float4*)(xbase + (size_t)(idx >> 4) * 1024
                                         + (sk + 1) * 64 + (idx & 15) * 4);
            }
        }
#pragma unroll
        for (int ks = 0; ks < 2; ks++) {
            s8v a0 = *(const s8v*)&xl[cur][rhalf + l16][ks * 32 + quad * 8];
            s8v a1 = *(const s8v*)&xl[cur][rhalf + 16 + l16][ks * 32 + quad * 8];
            int kg = sk * 2 + ks;
#pragma unroll
            for (int i = 0; i < 3; i++) {
                s8v bf = wp[((tbase + i) * 32 + kg) * 64 + lane];  // lane-contig
                acc[0][i] = MFMA16(a0, bf, acc[0][i]);
                acc[1][i] = MFMA16(a1, bf, acc[1][i]);
            }
        }
        if (sk < 15) {                    // convert + stage into other buffer
#pragma unroll
            for (int i = 0; i < 2; i++) {
                int idx = i * 512 + tid;
                *(s4v*)&xl[nxt][idx >> 4][(idx & 15) * 4] = cvt4(xr[i]);
            }
            __syncthreads();
        }
    }

    // epilogue: C/D rows = quad*4+r (+rf*16), col = nt*16+l16
    int b = row0 >> 11;
#pragma unroll
    for (int rf = 0; rf < 2; rf++) {
        int rowD = row0 + rhalf + rf * 16 + quad * 4;
#pragma unroll
        for (int i = 0; i < 3; i++) {
            int t = tbase + i, m3 = t >> 2, nt = t & 3;
            int col = nt * 16 + l16;
            if (m3 == 0) {
                float bias = bq[col] * 0.03125f;
#pragma unroll
                for (int r = 0; r < 4; r++)
                    qws[(rowD + r) * 64 + col] = f2bf(acc[rf][i][r] + bias);
            } else if (m3 == 1) {
                float bias = bk[col];
#pragma unroll
                for (int r = 0; r < 4; r++)
                    kws[(rowD + r) * 64 + col] = f2bf(acc[rf][i][r] + bias);
            } else {
                float bias = bv[col];
                int keyb = rowD & 2047;
                s4v v4;
#pragma unroll
                for (int r = 0; r < 4; r++) v4[r] = f2bf(acc[rf][i][r] + bias);
                *(s4v*)(vt + (size_t)(b * 64 + col) * 2048 + keyb) = v4;
            }
        }
    }
}

// ---------------------------------------------------------------------------
// Kernel 2: split-K attention. grid(144,8) x 256 thr. Block = one work unit
// (qt64, cc): 64 q-rows x 256-key chunk (<=4 j-tiles). K/V^T tiles staged in
// PING-PONG LDS buffers with register prefetch of tile t+1 before computing
// tile t -> ONE barrier per tile, load latency hidden behind compute.
// Lane-contiguous staging. No softmax max-subtraction (|s|<~1); row-sum via
// ones-column MFMA tile. Un-normalized partials; combine divides.
// ---------------------------------------------------------------------------
__global__ __launch_bounds__(256) void attn_kernel(
    const short* __restrict__ qws, const short* __restrict__ kws,
    const short* __restrict__ vt, short* __restrict__ opart,
    float* __restrict__ lpart)
{
    __shared__ short Kl[2][64][72];     // 18432 B
    __shared__ short Vl[2][64][72];     // 18432 B
    __shared__ short Pl[4][16 * 72];    // 9216 B

    int tid  = threadIdx.x;
    int wave = tid >> 6, lane = tid & 63;
    int quad = lane >> 4, l16 = lane & 15;
    int b = blockIdx.y;
    int u = 143 - blockIdx.x;            // biggest units dispatch first

    // decode u -> (qt,cc): qt-group g (qt=4g..4g+3) starts at 2g(g+1)
    int g = 0;
#pragma unroll
    for (int gg = 1; gg <= 7; gg++) if (u >= 2 * gg * (gg + 1)) g = gg;
    int rem = u - 2 * g * (g + 1);
    int qt = 4 * g + rem / (g + 1);
    int cc = rem % (g + 1);

    int q0 = qt * 64;
    int c0 = cc * 256;
    bool last = (cc == g);
    int jtN = last ? (((q0 + 63 - c0) >> 6) + 1) : 4;

    const short* qb  = qws + (size_t)b * 2048 * 64;
    const short* kb  = kws + (size_t)b * 2048 * 64;
    const short* vtb = vt  + (size_t)b * 64 * 2048;

    // Q A-frags: wave's 16 rows (m=l16), k = quad*8 (+32)
    int qrow = q0 + wave * 16 + l16;
    s8v qf0 = *(const s8v*)(qb + qrow * 64 + quad * 8);
    s8v qf1 = *(const s8v*)(qb + qrow * 64 + 32 + quad * 8);

    s8v onef;                            // B col 0 == 1.0 -> row sums
#pragma unroll
    for (int j = 0; j < 8; j++) onef[j] = (l16 == 0) ? (short)0x3F80 : (short)0;

    f4v o[5];
    f4v z = {0.f, 0.f, 0.f, 0.f};
#pragma unroll
    for (int nt = 0; nt < 5; nt++) o[nt] = z;

    int srow = tid >> 3;                 // staging row 0..31 (+32 on i=1)
    int sc   = (tid & 7) * 8;            // 16B chunk within 128B row

    // prologue: stage tile 0 into buffer 0
    s8v kr[2], vr[2];
#pragma unroll
    for (int i = 0; i < 2; i++) {
        int r = srow + i * 32;
        kr[i] = *(const s8v*)(kb + (c0 + r) * 64 + sc);
        vr[i] = *(const s8v*)(vtb + (size_t)r * 2048 + c0 + sc);
    }
#pragma unroll
    for (int i = 0; i < 2; i++) {
        int r = srow + i * 32;
        *(s8v*)&Kl[0][r][sc] = kr[i];
        *(s8v*)&Vl[0][r][sc] = vr[i];
    }
    __syncthreads();

    for (int t = 0; t < jtN; t++) {
        int cur = t & 1, nxt = cur ^ 1;
        int key0 = c0 + t * 64;
        bool more = (t + 1 < jtN);

        // ---- issue next tile's global loads (consumed after compute) ----
        if (more) {
            int key1 = key0 + 64;
#pragma unroll
            for (int i = 0; i < 2; i++) {
                int r = srow + i * 32;
                kr[i] = *(const s8v*)(kb + (key1 + r) * 64 + sc);
                vr[i] = *(const s8v*)(vtb + (size_t)r * 2048 + key1 + sc);
            }
        }

        // ---- S = Q K^T ----
        f4v s[4];
#pragma unroll
        for (int nt = 0; nt < 4; nt++) {
            s8v k0 = *(const s8v*)&Kl[cur][nt * 16 + l16][quad * 8];
            s8v k1 = *(const s8v*)&Kl[cur][nt * 16 + l16][32 + quad * 8];
            s[nt] = MFMA16(qf0, k0, z);
            s[nt] = MFMA16(qf1, k1, s[nt]);
        }

        // ---- causal mask (any tile of the diagonal chunk) ----
        if (last) {
            int rowbase = q0 + wave * 16 + quad * 4;
#pragma unroll
            for (int nt = 0; nt < 4; nt++) {
                int key = key0 + nt * 16 + l16;
#pragma unroll
                for (int r = 0; r < 4; r++)
                    if (key > rowbase + r) s[nt][r] = -1e30f;
            }
        }

        // ---- p = exp(s): C-layout -> wave-private LDS -> A-layout ----
        short* pw = Pl[wave];
#pragma unroll
        for (int nt = 0; nt < 4; nt++)
#pragma unroll
            for (int r = 0; r < 4; r++)
                pw[(quad * 4 + r) * 72 + nt * 16 + l16] = f2bf(__expf(s[nt][r]));
        asm volatile("s_waitcnt lgkmcnt(0)" ::: "memory");

        // ---- O += P V (tile 4 = ones column -> l) ----
#pragma unroll
        for (int st = 0; st < 2; st++) {
            s8v pf = *(const s8v*)(pw + l16 * 72 + st * 32 + quad * 8);
#pragma unroll
            for (int nt = 0; nt < 4; nt++) {
                s8v vf = *(const s8v*)&Vl[cur][nt * 16 + l16][st * 32 + quad * 8];
                o[nt] = MFMA16(pf, vf, o[nt]);
            }
            o[4] = MFMA16(pf, onef, o[4]);
        }

        // ---- write prefetched tile into other buffer; single barrier ----
        if (more) {
#pragma unroll
            for (int i = 0; i < 2; i++) {
                int r = srow + i * 32;
                *(s8v*)&Kl[nxt][r][sc] = kr[i];
                *(s8v*)&Vl[nxt][r][sc] = vr[i];
            }
            __syncthreads();
        }
    }

    // ---- write un-normalized partials ----
    int g0 = b * 2048 + q0 + wave * 16;
    short* op = opart + (size_t)cc * (16384 * 64);
#pragma unroll
    for (int nt = 0; nt < 4; nt++)
#pragma unroll
        for (int r = 0; r < 4; r++)
            op[(size_t)(g0 + quad * 4 + r) * 64 + nt * 16 + l16] = f2bf(o[nt][r]);
    if (l16 == 0) {
        float* lp = lpart + (size_t)cc * 16384;
#pragma unroll
        for (int r = 0; r < 4; r++) lp[g0 + quad * 4 + r] = o[4][r];
    }
}

// ---------------------------------------------------------------------------
// Kernel 3: combine partials. out[g][d] = sum_c O_c[g][d] / sum_c l_c[g].
// ---------------------------------------------------------------------------
__global__ __launch_bounds__(256) void combine_kernel(
    const short* __restrict__ opart, const float* __restrict__ lpart,
    float* __restrict__ out)
{
    int idx = blockIdx.x * 256 + threadIdx.x;   // 0..262143
    int g = idx >> 4;                            // global row
    int d = (idx & 15) * 4;
    int nc = ((g & 2047) >> 8) + 1;              // 256-key chunks for this row
    float s0 = 0.f, s1 = 0.f, s2 = 0.f, s3 = 0.f, lsum = 0.f;
    for (int c = 0; c < nc; c++) {
        short4 o4 = *(const short4*)(opart + (size_t)c * (16384 * 64) + g * 64 + d);
        s0 += bf2f(o4.x); s1 += bf2f(o4.y); s2 += bf2f(o4.z); s3 += bf2f(o4.w);
        lsum += lpart[c * 16384 + g];
    }
    float inv = 1.0f / lsum;
    float4 res = {s0 * inv, s1 * inv, s2 * inv, s3 * inv};
    *(float4*)(out + g * 64 + d) = res;
}

// ---------------------------------------------------------------------------
extern "C" void kernel_launch(void* const* d_in, const int* in_sizes, int n_in,
                              void* d_out, int out_size, void* d_ws, size_t ws_size,
                              hipStream_t stream) {
    const float* x  = (const float*)d_in[0];
    const float* wq = (const float*)d_in[1];
    const float* bq = (const float*)d_in[2];
    const float* wk = (const float*)d_in[3];
    const float* bk = (const float*)d_in[4];
    const float* wv = (const float*)d_in[5];
    const float* bv = (const float*)d_in[6];
    float* out = (float*)d_out;

    char* ws = (char*)d_ws;
    short* wpack = (short*)ws;                               // 384 KiB @ 0
    short* qws   = (short*)(ws + (512u << 10));              // 2 MiB
    short* kws   = (short*)(ws + (512u << 10) + (2u << 20)); // 2 MiB
    short* vt    = (short*)(ws + (512u << 10) + (4u << 20)); // 2 MiB [b][dim][key]
    short* opart = (short*)(ws + (512u << 10) + (6u << 20)); // 16 MiB, 8 planes
    float* lpart = (float*)(ws + (512u << 10) + (22u << 20));// 512 KiB

    hipLaunchKernelGGL(pack_w_kernel,  dim3(96),        dim3(256), 0, stream,
                       wq, wk, wv, wpack);
    hipLaunchKernelGGL(qkv_kernel,     dim3(256),       dim3(512), 0, stream,
                       x, wpack, bq, bk, bv, qws, kws, vt);
    hipLaunchKernelGGL(attn_kernel,    dim3(144, 8),    dim3(256), 0, stream,
                       qws, kws, vt, opart, lpart);
    hipLaunchKernelGGL(combine_kernel, dim3(1024),      dim3(256), 0, stream,
                       opart, lpart, out);
}

// Round 8
// 134.757 us; speedup vs baseline: 1.0611x; 1.0611x over previous
//
#include <hip/hip_runtime.h>
#include <hip/hip_bf16.h>

typedef short s8v __attribute__((ext_vector_type(8)));   // 8 bf16 in 4 VGPRs
typedef short s4v __attribute__((ext_vector_type(4)));   // 4 bf16
typedef float f4v __attribute__((ext_vector_type(4)));   // MFMA accumulator

#define MFMA16(a,b,c) __builtin_amdgcn_mfma_f32_16x16x32_bf16((a),(b),(c),0,0,0)

__device__ __forceinline__ short f2bf(float f) {
    __hip_bfloat16 h = __float2bfloat16(f);
    short s; __builtin_memcpy(&s, &h, 2); return s;
}
__device__ __forceinline__ float bf2f(short s) {
    unsigned int u = ((unsigned int)(unsigned short)s) << 16;
    float f; __builtin_memcpy(&f, &u, 4); return f;
}
__device__ __forceinline__ s4v cvt4(float4 a) {
    s4v r; r[0] = f2bf(a.x); r[1] = f2bf(a.y); r[2] = f2bf(a.z); r[3] = f2bf(a.w);
    return r;
}
// pack two floats -> one dword of 2 bf16 (lo = a, hi = b)
__device__ __forceinline__ unsigned int pk2(float a, float b) {
    return ((unsigned int)(unsigned short)f2bf(b) << 16) |
           (unsigned int)(unsigned short)f2bf(a);
}

// ---------------------------------------------------------------------------
// Kernel 0: repack wq/wk/wv [1024,64] fp32 -> bf16 B-fragment layout.
// Frag id = ((t*32)+ks)*64 + lane, t = m3*4+nt. Lane holds
// B[k = ks*32 + (lane>>4)*8 + j][col = nt*16 + (lane&15)], j=0..7.
// Scale 1/32 (C^-0.5) baked into wq.
// ---------------------------------------------------------------------------
__global__ __launch_bounds__(256) void pack_w_kernel(
    const float* __restrict__ wq, const float* __restrict__ wk,
    const float* __restrict__ wv, short* __restrict__ wpack)
{
    int fid  = blockIdx.x * 256 + threadIdx.x;   // 0..24575
    int lane = fid & 63;
    int ks   = (fid >> 6) & 31;
    int t    = fid >> 11;                        // 0..11
    int m3 = t >> 2, nt = t & 3;
    int col = nt * 16 + (lane & 15);
    int k0  = ks * 32 + (lane >> 4) * 8;
    const float* w = (m3 == 0) ? wq : (m3 == 1 ? wk : wv);
    float sc = (m3 == 0) ? 0.03125f : 1.0f;
    s8v frag;
#pragma unroll
    for (int j = 0; j < 8; j++) frag[j] = f2bf(w[(k0 + j) * 64 + col] * sc);
    ((s8v*)wpack)[fid] = frag;
}

// ---------------------------------------------------------------------------
// Kernel 1: unified QKV GEMM (R6 config — unchanged). grid(512) x 256 thr.
// Block = 32 token rows x 192 cols; lane-contiguous staging; reg->LDS
// double buffer; wave = 32 rows x 48 cols. LDS stride 136.
// V stored TRANSPOSED vt[b][dim][key], s4v-packed.
// ---------------------------------------------------------------------------
__global__ __launch_bounds__(256) void qkv_kernel(
    const float* __restrict__ x, const short* __restrict__ wpack,
    const float* __restrict__ bq, const float* __restrict__ bk,
    const float* __restrict__ bv,
    short* __restrict__ qws, short* __restrict__ kws, short* __restrict__ vt)
{
    __shared__ short xl[2][32][136];     // 17408 B

    int tid  = threadIdx.x;
    int wave = tid >> 6, lane = tid & 63;
    int quad = lane >> 4, l16 = lane & 15;
    int row0 = blockIdx.x * 32;
    const float* xbase = x + (size_t)row0 * 1024;
    const s8v* wp = (const s8v*)wpack;
    int tbase = wave * 3;                // wave's 3 wp tiles: tbase..tbase+2

    f4v acc[2][3];
    f4v z = {0.f, 0.f, 0.f, 0.f};
#pragma unroll
    for (int rf = 0; rf < 2; rf++)
#pragma unroll
        for (int i = 0; i < 3; i++) acc[rf][i] = z;

    float4 xr[4];
    // prologue: stage slice 0 (rows=idx>>5, float4-col=idx&31 -> coalesced)
#pragma unroll
    for (int i = 0; i < 4; i++) {
        int idx = i * 256 + tid;
        xr[i] = *(const float4*)(xbase + (size_t)(idx >> 5) * 1024 + (idx & 31) * 4);
    }
#pragma unroll
    for (int i = 0; i < 4; i++) {
        int idx = i * 256 + tid;
        *(s4v*)&xl[0][idx >> 5][(idx & 31) * 4] = cvt4(xr[i]);
    }
    __syncthreads();

    for (int sk = 0; sk < 8; sk++) {
        int cur = sk & 1, nxt = cur ^ 1;
        if (sk < 7) {                     // issue next slice's global loads
#pragma unroll
            for (int i = 0; i < 4; i++) {
                int idx = i * 256 + tid;
                xr[i] = *(const float4*)(xbase + (size_t)(idx >> 5) * 1024
                                         + (sk + 1) * 128 + (idx & 31) * 4);
            }
        }
#pragma unroll
        for (int ks = 0; ks < 4; ks++) {
            s8v a0 = *(const s8v*)&xl[cur][l16][ks * 32 + quad * 8];
            s8v a1 = *(const s8v*)&xl[cur][16 + l16][ks * 32 + quad * 8];
            int kg = sk * 4 + ks;
#pragma unroll
            for (int i = 0; i < 3; i++) {
                s8v bf = wp[((tbase + i) * 32 + kg) * 64 + lane];  // lane-contig
                acc[0][i] = MFMA16(a0, bf, acc[0][i]);
                acc[1][i] = MFMA16(a1, bf, acc[1][i]);
            }
        }
        if (sk < 7) {                     // convert + stage into other buffer
#pragma unroll
            for (int i = 0; i < 4; i++) {
                int idx = i * 256 + tid;
                *(s4v*)&xl[nxt][idx >> 5][(idx & 31) * 4] = cvt4(xr[i]);
            }
        }
        __syncthreads();
    }

    // epilogue: C/D rows = quad*4+r (+rf*16), col = nt*16+l16
    int b = row0 >> 11;
#pragma unroll
    for (int rf = 0; rf < 2; rf++) {
        int rowD = row0 + rf * 16 + quad * 4;
#pragma unroll
        for (int i = 0; i < 3; i++) {
            int t = tbase + i, m3 = t >> 2, nt = t & 3;
            int col = nt * 16 + l16;
            if (m3 == 0) {
                float bias = bq[col] * 0.03125f;
#pragma unroll
                for (int r = 0; r < 4; r++)
                    qws[(rowD + r) * 64 + col] = f2bf(acc[rf][i][r] + bias);
            } else if (m3 == 1) {
                float bias = bk[col];
#pragma unroll
                for (int r = 0; r < 4; r++)
                    kws[(rowD + r) * 64 + col] = f2bf(acc[rf][i][r] + bias);
            } else {
                float bias = bv[col];
                int keyb = rowD & 2047;
                s4v v4;
#pragma unroll
                for (int r = 0; r < 4; r++) v4[r] = f2bf(acc[rf][i][r] + bias);
                *(s4v*)(vt + (size_t)(b * 64 + col) * 2048 + keyb) = v4;
            }
        }
    }
}

// ---------------------------------------------------------------------------
// Kernel 2: split-K attention. grid(144,8) x 256 thr. Block = one work unit
// (qt64, cc): 64 q-rows x 256-key chunk (<=4 j-tiles). SINGLE K/V LDS buffer
// (27.6 KB -> 5 blocks/CU) + register prefetch of tile t+1 before compute.
// S computed TRANSPOSED (swap MFMA operands: S^T = K*Q^T, frag data
// identical) so each lane holds 4 CONSECUTIVE keys per q-row -> P written to
// LDS as packed ds_write_b64 (4 ops vs 16 scalar). Row-sum l via ones-column
// MFMA. Un-normalized partials; combine divides.
// ---------------------------------------------------------------------------
__global__ __launch_bounds__(256) void attn_kernel(
    const short* __restrict__ qws, const short* __restrict__ kws,
    const short* __restrict__ vt, short* __restrict__ opart,
    float* __restrict__ lpart)
{
    __shared__ short Kl[64][72];        // 9216 B  K[key][dim]
    __shared__ short Vl[64][72];        // 9216 B  V^T[dim][key]
    __shared__ short Pl[4][16 * 72];    // 9216 B  per-wave P[qrow][key]

    int tid  = threadIdx.x;
    int wave = tid >> 6, lane = tid & 63;
    int quad = lane >> 4, l16 = lane & 15;
    int b = blockIdx.y;
    int u = 143 - blockIdx.x;            // biggest units dispatch first

    // decode u -> (qt,cc): qt-group g (qt=4g..4g+3) starts at 2g(g+1)
    int g = 0;
#pragma unroll
    for (int gg = 1; gg <= 7; gg++) if (u >= 2 * gg * (gg + 1)) g = gg;
    int rem = u - 2 * g * (g + 1);
    int qt = 4 * g + rem / (g + 1);
    int cc = rem % (g + 1);

    int q0 = qt * 64;
    int c0 = cc * 256;
    bool last = (cc == g);
    int jtN = last ? (((q0 + 63 - c0) >> 6) + 1) : 4;

    const short* qb  = qws + (size_t)b * 2048 * 64;
    const short* kb  = kws + (size_t)b * 2048 * 64;
    const short* vtb = vt  + (size_t)b * 64 * 2048;

    // Q frags (B-operand for S^T; same per-lane data as A-operand)
    int qrow = q0 + wave * 16 + l16;
    s8v qf0 = *(const s8v*)(qb + qrow * 64 + quad * 8);
    s8v qf1 = *(const s8v*)(qb + qrow * 64 + 32 + quad * 8);

    s8v onef;                            // B col 0 == 1.0 -> row sums
#pragma unroll
    for (int j = 0; j < 8; j++) onef[j] = (l16 == 0) ? (short)0x3F80 : (short)0;

    f4v o[5];
    f4v z = {0.f, 0.f, 0.f, 0.f};
#pragma unroll
    for (int nt = 0; nt < 5; nt++) o[nt] = z;

    int srow = tid >> 3;                 // staging row 0..31 (+32 on i=1)
    int sc   = (tid & 7) * 8;            // 16B chunk within 128B row

    // prologue: prefetch tile 0 into registers
    s8v kr[2], vr[2];
#pragma unroll
    for (int i = 0; i < 2; i++) {
        int r = srow + i * 32;
        kr[i] = *(const s8v*)(kb + (c0 + r) * 64 + sc);
        vr[i] = *(const s8v*)(vtb + (size_t)r * 2048 + c0 + sc);
    }

    for (int t = 0; t < jtN; t++) {
        int key0 = c0 + t * 64;
        bool more = (t + 1 < jtN);

        // ---- commit prefetched tile to LDS (single buffer) ----
        __syncthreads();                 // prior tile's LDS reads done
#pragma unroll
        for (int i = 0; i < 2; i++) {
            int r = srow + i * 32;
            *(s8v*)&Kl[r][sc] = kr[i];
            *(s8v*)&Vl[r][sc] = vr[i];
        }
        __syncthreads();

        // ---- issue next tile's global loads; consumed after compute ----
        if (more) {
            int key1 = key0 + 64;
#pragma unroll
            for (int i = 0; i < 2; i++) {
                int r = srow + i * 32;
                kr[i] = *(const s8v*)(kb + (key1 + r) * 64 + sc);
                vr[i] = *(const s8v*)(vtb + (size_t)r * 2048 + key1 + sc);
            }
        }

        // ---- S^T = K Q^T : s[nt][r] = S[qrow=l16][key0+nt*16+quad*4+r] ----
        f4v s[4];
#pragma unroll
        for (int nt = 0; nt < 4; nt++) {
            s8v k0 = *(const s8v*)&Kl[nt * 16 + l16][quad * 8];
            s8v k1 = *(const s8v*)&Kl[nt * 16 + l16][32 + quad * 8];
            s[nt] = MFMA16(k0, qf0, z);
            s[nt] = MFMA16(k1, qf1, s[nt]);
        }

        // ---- causal mask (diagonal chunk only) ----
        if (last) {
            int qg = q0 + wave * 16 + l16;
#pragma unroll
            for (int nt = 0; nt < 4; nt++) {
                int keyb = key0 + nt * 16 + quad * 4;
#pragma unroll
                for (int r = 0; r < 4; r++)
                    if (keyb + r > qg) s[nt][r] = -1e30f;
            }
        }

        // ---- p = exp(s): 4 consecutive keys/lane -> packed ds_write_b64 ----
        short* pw = Pl[wave];
#pragma unroll
        for (int nt = 0; nt < 4; nt++) {
            uint2 d;
            d.x = pk2(__expf(s[nt][0]), __expf(s[nt][1]));
            d.y = pk2(__expf(s[nt][2]), __expf(s[nt][3]));
            *(uint2*)&pw[l16 * 72 + nt * 16 + quad * 4] = d;
        }
        asm volatile("s_waitcnt lgkmcnt(0)" ::: "memory");

        // ---- O += P V (tile 4 = ones column -> l) ----
#pragma unroll
        for (int st = 0; st < 2; st++) {
            s8v pf = *(const s8v*)(pw + l16 * 72 + st * 32 + quad * 8);
#pragma unroll
            for (int nt = 0; nt < 4; nt++) {
                s8v vf = *(const s8v*)&Vl[nt * 16 + l16][st * 32 + quad * 8];
                o[nt] = MFMA16(pf, vf, o[nt]);
            }
            o[4] = MFMA16(pf, onef, o[4]);
        }
    }

    // ---- write un-normalized partials ----
    int g0 = b * 2048 + q0 + wave * 16;
    short* op = opart + (size_t)cc * (16384 * 64);
#pragma unroll
    for (int nt = 0; nt < 4; nt++)
#pragma unroll
        for (int r = 0; r < 4; r++)
            op[(size_t)(g0 + quad * 4 + r) * 64 + nt * 16 + l16] = f2bf(o[nt][r]);
    if (l16 == 0) {
        float* lp = lpart + (size_t)cc * 16384;
#pragma unroll
        for (int r = 0; r < 4; r++) lp[g0 + quad * 4 + r] = o[4][r];
    }
}

// ---------------------------------------------------------------------------
// Kernel 3: combine partials. out[g][d] = sum_c O_c[g][d] / sum_c l_c[g].
// ---------------------------------------------------------------------------
__global__ __launch_bounds__(256) void combine_kernel(
    const short* __restrict__ opart, const float* __restrict__ lpart,
    float* __restrict__ out)
{
    int idx = blockIdx.x * 256 + threadIdx.x;   // 0..262143
    int g = idx >> 4;                            // global row
    int d = (idx & 15) * 4;
    int nc = ((g & 2047) >> 8) + 1;              // 256-key chunks for this row
    float s0 = 0.f, s1 = 0.f, s2 = 0.f, s3 = 0.f, lsum = 0.f;
    for (int c = 0; c < nc; c++) {
        short4 o4 = *(const short4*)(opart + (size_t)c * (16384 * 64) + g * 64 + d);
        s0 += bf2f(o4.x); s1 += bf2f(o4.y); s2 += bf2f(o4.z); s3 += bf2f(o4.w);
        lsum += lpart[c * 16384 + g];
    }
    float inv = 1.0f / lsum;
    float4 res = {s0 * inv, s1 * inv, s2 * inv, s3 * inv};
    *(float4*)(out + g * 64 + d) = res;
}

// ---------------------------------------------------------------------------
extern "C" void kernel_launch(void* const* d_in, const int* in_sizes, int n_in,
                              void* d_out, int out_size, void* d_ws, size_t ws_size,
                              hipStream_t stream) {
    const float* x  = (const float*)d_in[0];
    const float* wq = (const float*)d_in[1];
    const float* bq = (const float*)d_in[2];
    const float* wk = (const float*)d_in[3];
    const float* bk = (const float*)d_in[4];
    const float* wv = (const float*)d_in[5];
    const float* bv = (const float*)d_in[6];
    float* out = (float*)d_out;

    char* ws = (char*)d_ws;
    short* wpack = (short*)ws;                               // 384 KiB @ 0
    short* qws   = (short*)(ws + (512u << 10));              // 2 MiB
    short* kws   = (short*)(ws + (512u << 10) + (2u << 20)); // 2 MiB
    short* vt    = (short*)(ws + (512u << 10) + (4u << 20)); // 2 MiB [b][dim][key]
    short* opart = (short*)(ws + (512u << 10) + (6u << 20)); // 16 MiB, 8 planes
    float* lpart = (float*)(ws + (512u << 10) + (22u << 20));// 512 KiB

    hipLaunchKernelGGL(pack_w_kernel,  dim3(96),        dim3(256), 0, stream,
                       wq, wk, wv, wpack);
    hipLaunchKernelGGL(qkv_kernel,     dim3(512),       dim3(256), 0, stream,
                       x, wpack, bq, bk, bv, qws, kws, vt);
    hipLaunchKernelGGL(attn_kernel,    dim3(144, 8),    dim3(256), 0, stream,
                       qws, kws, vt, opart, lpart);
    hipLaunchKernelGGL(combine_kernel, dim3(1024),      dim3(256), 0, stream,
                       opart, lpart, out);
}